// Round 3
// baseline (677.794 us; speedup 1.0000x reference)
//
#include <hip/hip_runtime.h>

#define INPUT_SIZE 32768
#define NUM_COLS   4096
#define NUM_ACTIVE 82
#define ROWS_PER_BLOCK 2
#define NF4 (INPUT_SIZE / 4)   // 8192 float4 per row

typedef float v4f __attribute__((ext_vector_type(4)));

__device__ __forceinline__ float dot4(v4f a, v4f b) {
    return a.x * b.x + a.y * b.y + a.z * b.z + a.w * b.w;
}

// Kernel A: boosted overlap = (connections @ input) * boost.
// 2 rows per block, 256 threads, grid=2048 -> 8 blocks/CU = 32 waves/CU
// (max occupancy, fill-kernel-like TLP). Plain cached loads (no nt).
// Sums of 0/1 products are exact integers in fp32 -> bit-exact vs numpy.
__global__ __launch_bounds__(256) void matvec_boost_kernel(
    const float* __restrict__ conn, const float* __restrict__ input,
    const float* __restrict__ boost, float* __restrict__ overlap)
{
    const int r0 = blockIdx.x * ROWS_PER_BLOCK;
    const int t  = threadIdx.x;
    const v4f* in4  = (const v4f*)input;
    const v4f* row0 = (const v4f*)(conn + (size_t)(r0 + 0) * INPUT_SIZE);
    const v4f* row1 = (const v4f*)(conn + (size_t)(r0 + 1) * INPUT_SIZE);

    float acc0 = 0.f, acc1 = 0.f;

    // 8192 slots / 256 threads = 32 per thread; 2 slots per iteration.
    for (int k = t; k < NF4; k += 512) {
        const int k2 = k + 256;
        v4f b0 = in4[k];
        v4f b1 = in4[k2];
        v4f a00 = row0[k];
        v4f a01 = row0[k2];
        v4f a10 = row1[k];
        v4f a11 = row1[k2];
        acc0 += dot4(a00, b0) + dot4(a01, b1);
        acc1 += dot4(a10, b0) + dot4(a11, b1);
    }

    // wave64 shuffle reduce each accumulator
    #pragma unroll
    for (int off = 32; off > 0; off >>= 1) {
        acc0 += __shfl_down(acc0, off, 64);
        acc1 += __shfl_down(acc1, off, 64);
    }

    __shared__ float part[4][ROWS_PER_BLOCK];
    const int wave = t >> 6;
    if ((t & 63) == 0) {
        part[wave][0] = acc0;
        part[wave][1] = acc1;
    }
    __syncthreads();
    if (t < ROWS_PER_BLOCK) {
        float tot = part[0][t] + part[1][t] + part[2][t] + part[3][t];
        overlap[r0 + t] = tot * boost[r0 + t];
    }
}

// Kernel B: exact stable top-k membership. One wave per column.
// rank(c) = #{ j : v_j > v_c  OR  (v_j == v_c AND j < c) } — matches
// jax.lax.top_k's lowest-index tie-break. active iff rank < 82.
__global__ __launch_bounds__(64) void topk_mask_kernel(
    const float* __restrict__ vals, float* __restrict__ out)
{
    const int c = blockIdx.x;
    const int lane = threadIdx.x;
    const float v = vals[c];
    const float4* v4 = (const float4*)vals;

    int cnt = 0;
    #pragma unroll
    for (int k = 0; k < NUM_COLS / 4 / 64; ++k) {   // 16 iterations
        const int i4 = lane + 64 * k;
        float4 b = v4[i4];
        const int j = i4 * 4;
        cnt += (b.x > v) || (b.x == v && (j + 0) < c);
        cnt += (b.y > v) || (b.y == v && (j + 1) < c);
        cnt += (b.z > v) || (b.z == v && (j + 2) < c);
        cnt += (b.w > v) || (b.w == v && (j + 3) < c);
    }
    #pragma unroll
    for (int off = 32; off > 0; off >>= 1)
        cnt += __shfl_down(cnt, off, 64);

    if (lane == 0) {
        const bool act = cnt < NUM_ACTIVE;
        out[c] = act ? 1.0f : 0.0f;
        out[NUM_COLS + c] = act ? v : 0.0f;
    }
}

extern "C" void kernel_launch(void* const* d_in, const int* in_sizes, int n_in,
                              void* d_out, int out_size, void* d_ws, size_t ws_size,
                              hipStream_t stream) {
    const float* input = (const float*)d_in[0];   // [32768]
    const float* conn  = (const float*)d_in[1];   // [4096, 32768]
    const float* boost = (const float*)d_in[2];   // [4096]
    float* out = (float*)d_out;                   // [8192]: mask then masked-boosted
    float* ov  = (float*)d_ws;                    // [4096] boosted overlaps

    matvec_boost_kernel<<<NUM_COLS / ROWS_PER_BLOCK, 256, 0, stream>>>(conn, input, boost, ov);
    topk_mask_kernel<<<NUM_COLS, 64, 0, stream>>>(ov, out);
}

// Round 4
// 652.496 us; speedup vs baseline: 1.0388x; 1.0388x over previous
//
#include <hip/hip_runtime.h>

#define INPUT_SIZE 32768
#define NUM_COLS   4096
#define NUM_ACTIVE 82
#define ROWS_PER_BLOCK 8
#define NF4 (INPUT_SIZE / 4)   // 8192 float4 per row

typedef float v4f __attribute__((ext_vector_type(4)));

__device__ __forceinline__ float dot4(v4f a, v4f b) {
    return a.x * b.x + a.y * b.y + a.z * b.z + a.w * b.w;
}

// Kernel A: boosted overlap = (connections @ input) * boost.
// 8 rows per block, 256 threads, grid=512. conn is streamed once with
// nontemporal (evict-first) loads so it does not evict the L2-resident
// input vector; each input float4 amortizes over 8 rows.
// Sums of 0/1 products are exact integers in fp32 -> bit-exact vs numpy.
__global__ __launch_bounds__(256) void matvec_boost_kernel(
    const float* __restrict__ conn, const float* __restrict__ input,
    const float* __restrict__ boost, float* __restrict__ overlap)
{
    const int r0 = blockIdx.x * ROWS_PER_BLOCK;
    const int t  = threadIdx.x;
    const v4f* in4 = (const v4f*)input;
    const v4f* row[ROWS_PER_BLOCK];
    #pragma unroll
    for (int r = 0; r < ROWS_PER_BLOCK; ++r)
        row[r] = (const v4f*)(conn + (size_t)(r0 + r) * INPUT_SIZE);

    float acc[ROWS_PER_BLOCK];
    #pragma unroll
    for (int r = 0; r < ROWS_PER_BLOCK; ++r) acc[r] = 0.f;

    // 8192 slots / 256 threads = 32 per thread; 2 slots per iteration.
    for (int k = t; k < NF4; k += 512) {
        const int k2 = k + 256;
        v4f b0 = in4[k];
        v4f b1 = in4[k2];
        v4f a0[ROWS_PER_BLOCK], a1[ROWS_PER_BLOCK];
        #pragma unroll
        for (int r = 0; r < ROWS_PER_BLOCK; ++r) {
            a0[r] = __builtin_nontemporal_load(&row[r][k]);
            a1[r] = __builtin_nontemporal_load(&row[r][k2]);
        }
        #pragma unroll
        for (int r = 0; r < ROWS_PER_BLOCK; ++r)
            acc[r] += dot4(a0[r], b0) + dot4(a1[r], b1);
    }

    // wave64 shuffle reduce each accumulator
    #pragma unroll
    for (int r = 0; r < ROWS_PER_BLOCK; ++r) {
        float a = acc[r];
        #pragma unroll
        for (int off = 32; off > 0; off >>= 1)
            a += __shfl_down(a, off, 64);
        acc[r] = a;
    }

    __shared__ float part[4][ROWS_PER_BLOCK];
    const int wave = t >> 6;
    if ((t & 63) == 0) {
        #pragma unroll
        for (int r = 0; r < ROWS_PER_BLOCK; ++r) part[wave][r] = acc[r];
    }
    __syncthreads();
    if (t < ROWS_PER_BLOCK) {
        float tot = part[0][t] + part[1][t] + part[2][t] + part[3][t];
        overlap[r0 + t] = tot * boost[r0 + t];
    }
}

// Kernel B: exact stable top-k membership. One wave per column.
// rank(c) = #{ j : v_j > v_c  OR  (v_j == v_c AND j < c) } — matches
// jax.lax.top_k's lowest-index tie-break. active iff rank < 82.
__global__ __launch_bounds__(64) void topk_mask_kernel(
    const float* __restrict__ vals, float* __restrict__ out)
{
    const int c = blockIdx.x;
    const int lane = threadIdx.x;
    const float v = vals[c];
    const float4* v4 = (const float4*)vals;

    int cnt = 0;
    #pragma unroll
    for (int k = 0; k < NUM_COLS / 4 / 64; ++k) {   // 16 iterations
        const int i4 = lane + 64 * k;
        float4 b = v4[i4];
        const int j = i4 * 4;
        cnt += (b.x > v) || (b.x == v && (j + 0) < c);
        cnt += (b.y > v) || (b.y == v && (j + 1) < c);
        cnt += (b.z > v) || (b.z == v && (j + 2) < c);
        cnt += (b.w > v) || (b.w == v && (j + 3) < c);
    }
    #pragma unroll
    for (int off = 32; off > 0; off >>= 1)
        cnt += __shfl_down(cnt, off, 64);

    if (lane == 0) {
        const bool act = cnt < NUM_ACTIVE;
        out[c] = act ? 1.0f : 0.0f;
        out[NUM_COLS + c] = act ? v : 0.0f;
    }
}

extern "C" void kernel_launch(void* const* d_in, const int* in_sizes, int n_in,
                              void* d_out, int out_size, void* d_ws, size_t ws_size,
                              hipStream_t stream) {
    const float* input = (const float*)d_in[0];   // [32768]
    const float* conn  = (const float*)d_in[1];   // [4096, 32768]
    const float* boost = (const float*)d_in[2];   // [4096]
    float* out = (float*)d_out;                   // [8192]: mask then masked-boosted
    float* ov  = (float*)d_ws;                    // [4096] boosted overlaps

    matvec_boost_kernel<<<NUM_COLS / ROWS_PER_BLOCK, 256, 0, stream>>>(conn, input, boost, ov);
    topk_mask_kernel<<<NUM_COLS, 64, 0, stream>>>(ov, out);
}